// Round 7
// baseline (392.664 us; speedup 1.0000x reference)
//
#include <hip/hip_runtime.h>
#include <hip/hip_cooperative_groups.h>

namespace cg = cooperative_groups;

// B=4, HG=WG=32 -> 1024 tokens/batch, 4096 total; D=768, NH=12, HD=64, K=7 (49 neighbors)
// R7: single cooperative mega-kernel. Three different qkv schedules all measured
// ~44us with ALL pipes idle (MFMA 11%, VALU 11%, HBM<15%, conflicts 0, FETCH
// compulsory) -> the time is not in kernel structure; suspected inter-kernel
// launch/drain gaps (35-50us unaccounted across rounds) and/or DVFS-inflated
// per-dispatch profiling numbers. Fuse all 4 stages into ONE dispatch:
// 256 blocks x 512 thr (1 block/CU, 128KB LDS union), grid.sync() between
// phases, proven R5/R6 phase bodies reused.

typedef __bf16 bf16x8 __attribute__((ext_vector_type(8)));
typedef short s16x4 __attribute__((ext_vector_type(4)));
typedef float f32x4 __attribute__((ext_vector_type(4)));

__device__ __forceinline__ unsigned short f2bf(float f) {
  unsigned u = __float_as_uint(f);
  u += 0x7fffu + ((u >> 16) & 1u);   // RNE
  return (unsigned short)(u >> 16);
}

template <typename T>
__device__ __forceinline__ void gld_lds16(const T* g, T* l) {
  __builtin_amdgcn_global_load_lds((const __attribute__((address_space(1))) void*)g,
                                   (__attribute__((address_space(3))) void*)l, 16, 0, 0);
}

union Smem {
  struct { unsigned short a[2][256 * 64]; unsigned short b[2][256 * 64]; } g;  // qkv: 128 KB
  struct { unsigned short k[2][256 * 64]; unsigned short v[2][64 * 256]; } n;  // natten: 2 units x 64 KB
  struct { unsigned short a[2][5][64 * 32]; unsigned short b[2][5][64 * 32]; } p;  // proj: 2 units x 40 KB
};

// ---------------- phase 1: fp32 -> bf16 conversion (grid-strided) ----------------
__device__ __forceinline__ void cvt_phase(int gid, int gstride,
                                          const float* __restrict__ x, const float* __restrict__ w1,
                                          const float* __restrict__ w2, unsigned short* __restrict__ xo,
                                          unsigned short* __restrict__ w1o, unsigned short* __restrict__ w2o) {
  const int n1 = 4096 * 768 / 4;
  const int n2 = 2304 * 768 / 4;
  const int n3 = 768 * 768 / 4;
  for (int i = gid; i < n1 + n2 + n3; i += gstride) {
    float4 v;
    unsigned short* dst;
    int o;
    if (i < n1) {
      o = i; v = ((const float4*)x)[o]; dst = xo;
    } else if (i < n1 + n2) {
      o = i - n1; v = ((const float4*)w1)[o]; dst = w1o;
    } else {
      o = i - n1 - n2; v = ((const float4*)w2)[o]; dst = w2o;
    }
    ushort4 r;
    r.x = f2bf(v.x); r.y = f2bf(v.y); r.z = f2bf(v.z); r.w = f2bf(v.w);
    ((ushort4*)dst)[o] = r;
  }
}

// ---------------- phase 2: qkv GEMM, 8-phase 256x256 tile (R6 body) ----------------
__device__ __forceinline__ void qkv_tile(int tid, int bid,
                                         unsigned short (*sA)[256 * 64], unsigned short (*sB)[256 * 64],
                                         const unsigned short* __restrict__ A,
                                         const unsigned short* __restrict__ Bm,
                                         const float* __restrict__ bias,
                                         unsigned short* __restrict__ obf,
                                         unsigned short* __restrict__ vtout) {
  const int lane = tid & 63, wv = tid >> 6;
  const int wr = wv >> 2, wc = wv & 3;
  const int lr = lane & 15, lq = lane >> 4;

  const int wgid = (bid & 7) * 18 + (bid >> 3);
  const int bx = wgid % 9, by = wgid / 9;
  const int m0 = by * 256, n0 = bx * 256;

  const int srow = tid >> 3;
  const int sc8 = (tid & 7) * 8;
  const int scl8 = (((tid & 7) ^ ((tid >> 3) & 7))) * 8;  // pre-swizzled source chunk
  const unsigned short* gA = A + (size_t)(m0 + srow) * 768 + scl8;
  const unsigned short* gB = Bm + (size_t)(n0 + srow) * 768 + scl8;
  const int ldst = srow * 64 + sc8;

  f32x4 acc[8][4] = {};

#define STG(t, p)                                                                            \
  do {                                                                                       \
    unsigned short* dA = sA[(t) & 1];                                                        \
    unsigned short* dB = sB[(t) & 1];                                                        \
    const int ko = (t) * 64;                                                                 \
    gld_lds16(gA + (size_t)((p) * 128) * 768 + ko, dA + ((p) * 128) * 64 + ldst);            \
    gld_lds16(gA + (size_t)((p) * 128 + 64) * 768 + ko, dA + ((p) * 128 + 64) * 64 + ldst);  \
    gld_lds16(gB + (size_t)((p) * 128) * 768 + ko, dB + ((p) * 128) * 64 + ldst);            \
    gld_lds16(gB + (size_t)((p) * 128 + 64) * 768 + ko, dB + ((p) * 128 + 64) * 64 + ldst);  \
  } while (0)

  STG(0, 0);
  STG(0, 1);
  __builtin_amdgcn_sched_barrier(0);
  asm volatile("s_waitcnt vmcnt(0) lgkmcnt(0)" ::: "memory");
  __builtin_amdgcn_s_barrier();

  for (int t = 0; t < 12; ++t) {
    const unsigned short* cA = sA[t & 1];
    const unsigned short* cB = sB[t & 1];
    bf16x8 bfr[4][2];
#pragma unroll
    for (int nf = 0; nf < 4; ++nf)
#pragma unroll
      for (int ks = 0; ks < 2; ++ks)
        bfr[nf][ks] = *(const bf16x8*)(cB + (wc * 64 + nf * 16 + lr) * 64 +
                                       (((ks * 4 + lq) ^ (lr & 7)) << 3));
#pragma unroll
    for (int ph = 0; ph < 4; ++ph) {
      bf16x8 af[2][2];
#pragma unroll
      for (int i = 0; i < 2; ++i)
#pragma unroll
        for (int ks = 0; ks < 2; ++ks)
          af[i][ks] = *(const bf16x8*)(cA + (wr * 128 + (ph * 2 + i) * 16 + lr) * 64 +
                                       (((ks * 4 + lq) ^ (lr & 7)) << 3));
      if (ph < 2 && t + 1 < 12) STG(t + 1, ph);
      __builtin_amdgcn_s_barrier();
      __builtin_amdgcn_s_setprio(1);
#pragma unroll
      for (int i = 0; i < 2; ++i)
#pragma unroll
        for (int nf = 0; nf < 4; ++nf)
#pragma unroll
          for (int ks = 0; ks < 2; ++ks)
            acc[ph * 2 + i][nf] = __builtin_amdgcn_mfma_f32_16x16x32_bf16(
                af[i][ks], bfr[nf][ks], acc[ph * 2 + i][nf], 0, 0, 0);
      __builtin_amdgcn_s_setprio(0);
      if (ph == 3) {
        __builtin_amdgcn_sched_barrier(0);
        if (t + 1 < 12) asm volatile("s_waitcnt vmcnt(0)" ::: "memory");
      }
      __builtin_amdgcn_s_barrier();
    }
  }
#undef STG

  const int sidx = n0 / 768;
  if (sidx == 2) {
#pragma unroll
    for (int mf = 0; mf < 8; ++mf) {
#pragma unroll
      for (int nf = 0; nf < 4; ++nf) {
        int gn = n0 + wc * 64 + nf * 16 + lr;
        int rem = gn - 1536;
        int hh = rem >> 6, dd = gn & 63;
        float bsv = bias[gn];
        int gm0 = m0 + wr * 128 + mf * 16 + lq * 4;
        ushort4 pk;
        pk.x = f2bf(acc[mf][nf][0] + bsv);
        pk.y = f2bf(acc[mf][nf][1] + bsv);
        pk.z = f2bf(acc[mf][nf][2] + bsv);
        pk.w = f2bf(acc[mf][nf][3] + bsv);
        *(ushort4*)(vtout + (size_t)(hh * 64 + dd) * 4096 + gm0) = pk;
      }
    }
  } else {
    const float scale = (sidx == 0) ? 0.18033688f : 1.0f;  // 0.125 * log2(e) for Q
#pragma unroll
    for (int mf = 0; mf < 8; ++mf) {
#pragma unroll
      for (int nf = 0; nf < 4; ++nf) {
        int gn = n0 + wc * 64 + nf * 16 + lr;
        int rem = gn - sidx * 768;
        int hh = rem >> 6, dd = gn & 63;
        float bsv = bias[gn];
#pragma unroll
        for (int r = 0; r < 4; ++r) {
          int gm = m0 + wr * 128 + mf * 16 + lq * 4 + r;
          float val = (acc[mf][nf][r] + bsv) * scale;
          obf[((size_t)(sidx * 12 + hh) * 4096 + gm) * 64 + dd] = f2bf(val);
        }
      }
    }
  }
}

// ---------------- phase 3: natten unit (R0 body; Q direct from global) ----------------
__device__ __forceinline__ void natten_unit(int tid, unsigned short* sK, unsigned short* sVt,
                                            const unsigned short* __restrict__ qkvt,
                                            unsigned short* __restrict__ aout,
                                            int u, bool valid) {
  const int h = u % 12;
  const int rr = u / 12;
  const int ip = rr & 15, bz = rr >> 4;
  const int i0 = ip * 2;
  const int lane = tid & 63, wv = tid >> 6;
  const int lg = lane >> 4, lm = lane & 15;
  int si0 = i0 - 3; si0 = si0 < 0 ? 0 : si0; if (si0 > 25) si0 = 25;
  const int gb = bz * 1024;
  const unsigned short* Qg = qkvt + ((size_t)h * 4096 + gb + i0 * 32) * 64;
  const unsigned short* Kg = qkvt + ((size_t)(12 + h) * 4096 + gb) * 64;
  const unsigned short* Vg = qkvt + (size_t)24 * 4096 * 64 + (size_t)h * 64 * 4096 + gb;

#pragma unroll
  for (int it = 0; it < 8; ++it) {  // K: 256 tok x 64 d
    int f = it * 256 + tid;
    int t = f >> 3, c16 = f & 7;
    int wr = t >> 5, c = t & 31;
    int row = si0 + wr; if (row > 31) row = 31;
    uint4 v = *(const uint4*)(Kg + (row * 32 + c) * 64 + c16 * 8);
    int s = t & 15;
    *(uint2*)(sK + t * 64 + ((((c16 << 1)) ^ s) << 2)) = make_uint2(v.x, v.y);
    *(uint2*)(sK + t * 64 + ((((c16 << 1) | 1) ^ s) << 2)) = make_uint2(v.z, v.w);
  }
#pragma unroll
  for (int it = 0; it < 8; ++it) {  // Vt: 64 d x 256 tok
    int f = it * 256 + tid;
    int d = f >> 5, tc16 = f & 31;
    int wr = tc16 >> 2;
    int row = si0 + wr; if (row > 31) row = 31;
    uint4 v = *(const uint4*)(Vg + (size_t)d * 4096 + row * 32 + (tc16 & 3) * 8);
    int s = d & 15;
    *(uint2*)(sVt + d * 256 + ((((tc16 << 1)) ^ s) << 2)) = make_uint2(v.x, v.y);
    *(uint2*)(sVt + d * 256 + ((((tc16 << 1) | 1) ^ s) << 2)) = make_uint2(v.z, v.w);
  }
  __syncthreads();  // joint (both sub-units, uniform structure)

  const int row_sel = wv >> 1;
  const int jhalf = wv & 1;
  const int i = i0 + row_sel;
  int si_w = i - 3; si_w = si_w < 0 ? 0 : si_w; if (si_w > 25) si_w = 25;
  const int toff = (si_w - si0) * 32;
  const int j = jhalf * 16 + lm;
  int sj = j - 3; sj = sj < 0 ? 0 : sj; if (sj > 25) sj = 25;

  float madd[2][4];
#pragma unroll
  for (int p = 0; p < 2; ++p)
#pragma unroll
    for (int r = 0; r < 4; ++r) {
      int c = p * 16 + lg * 4 + r;
      madd[p][r] = (c >= sj && c <= sj + 6) ? 0.f : -1e30f;
    }

  // Q fragments direct from global (identical values to the old sQ path)
  s16x4 qf[4];
  const int qrow = row_sel * 32 + j;
#pragma unroll
  for (int ks = 0; ks < 4; ++ks)
    qf[ks] = *(const s16x4*)(Qg + qrow * 64 + ks * 16 + lg * 4);

  f32x4 accS[14];
#pragma unroll
  for (int tt = 0; tt < 14; ++tt) {
    f32x4 a = {0.f, 0.f, 0.f, 0.f};
    const int trow = toff + tt * 16 + lm;
    const unsigned short* kr = sK + trow * 64;
    const int sw = trow & 15;
#pragma unroll
    for (int ks = 0; ks < 4; ++ks) {
      s16x4 kf = *(const s16x4*)(kr + ((((ks << 2) + lg) ^ sw) << 2));
      a = __builtin_amdgcn_mfma_f32_16x16x16bf16_1k(kf, qf[ks], a, 0, 0, 0);
    }
    accS[tt] = a;
  }

  float mx = -3e38f;
#pragma unroll
  for (int tt = 0; tt < 14; ++tt)
#pragma unroll
    for (int r = 0; r < 4; ++r) {
      float v = accS[tt][r] + madd[tt & 1][r];
      accS[tt][r] = v;
      mx = fmaxf(mx, v);
    }
  mx = fmaxf(mx, __shfl_xor(mx, 16, 64));
  mx = fmaxf(mx, __shfl_xor(mx, 32, 64));
  float sum = 0.f;
#pragma unroll
  for (int tt = 0; tt < 14; ++tt)
#pragma unroll
    for (int r = 0; r < 4; ++r) {
      float p = exp2f(accS[tt][r] - mx);
      accS[tt][r] = p;
      sum += p;
    }
  sum += __shfl_xor(sum, 16, 64);
  sum += __shfl_xor(sum, 32, 64);
  const float inv = 1.f / sum;

  s16x4 pf[14];
#pragma unroll
  for (int tt = 0; tt < 14; ++tt) {
    union { unsigned u[2]; s16x4 v; } pk;
    pk.u[0] = ((unsigned)f2bf(accS[tt][1]) << 16) | f2bf(accS[tt][0]);
    pk.u[1] = ((unsigned)f2bf(accS[tt][3]) << 16) | f2bf(accS[tt][2]);
    pf[tt] = pk.v;
  }

  f32x4 accO[4] = {};
  const int choff = toff >> 2;
#pragma unroll
  for (int tt = 0; tt < 14; ++tt) {
    const int c8 = choff + tt * 4 + lg;
#pragma unroll
    for (int nt = 0; nt < 4; ++nt) {
      const int d = nt * 16 + lm;
      s16x4 vf = *(const s16x4*)(sVt + d * 256 + ((c8 ^ (d & 15)) << 2));
      accO[nt] = __builtin_amdgcn_mfma_f32_16x16x16bf16_1k(pf[tt], vf, accO[nt], 0, 0, 0);
    }
  }

  float invr[4];
#pragma unroll
  for (int r = 0; r < 4; ++r) invr[r] = __shfl(inv, lg * 4 + r, 64);

  if (valid) {
    const int tokbase = gb + i * 32 + jhalf * 16;
#pragma unroll
    for (int nt = 0; nt < 4; ++nt)
#pragma unroll
      for (int r = 0; r < 4; ++r) {
        int tok = tokbase + lg * 4 + r;
        aout[(size_t)tok * 768 + h * 64 + nt * 16 + lm] = f2bf(accO[nt][r] * invr[r]);
      }
  }
}

// ---------------- phase 4: proj unit, 64x64 tile, depth-4 counted pipeline (R5 body) ----------------
__device__ __forceinline__ void proj_unit(int t2, unsigned short (*sAu)[64 * 32], unsigned short (*sBu)[64 * 32],
                                          const unsigned short* __restrict__ A,
                                          const unsigned short* __restrict__ Bm,
                                          const float* __restrict__ bias,
                                          float* __restrict__ of32,
                                          int m0, int n0, bool valid) {
  const int lane = t2 & 63, wv = t2 >> 6;
  const int wrow = (wv >> 1) * 32, wcol = (wv & 1) * 32;
  const int lr = lane & 15, lq = lane >> 4;
  const int rchunk = (lq ^ ((lr >> 1) & 3)) * 8;
  f32x4 acc[2][2] = {};
  const int schunk = ((t2 & 3) ^ ((t2 >> 3) & 3)) * 8;
  const unsigned short* gA = A + (size_t)(m0 + (t2 >> 2)) * 768 + schunk;
  const unsigned short* gB = Bm + (size_t)(n0 + (t2 >> 2)) * 768 + schunk;

  // clean vmcnt base: counted waits below must not see outstanding stores
  asm volatile("s_waitcnt vmcnt(0)" ::: "memory");

#define PSTG(tile, buf)                               \
  do {                                                \
    gld_lds16(gA + (tile) * 32, sAu[(buf)] + t2 * 8); \
    gld_lds16(gB + (tile) * 32, sBu[(buf)] + t2 * 8); \
  } while (0)

#pragma unroll
  for (int t = 0; t < 4; ++t) PSTG(t, t);
  __builtin_amdgcn_sched_barrier(0);
  asm volatile("s_waitcnt vmcnt(6) lgkmcnt(0)" ::: "memory");
  __builtin_amdgcn_s_barrier();

  int rb = 0, sb = 4;
  for (int step = 0; step < 24; ++step) {
    const unsigned short* cA = sAu[rb];
    const unsigned short* cB = sBu[rb];
    bf16x8 af[2], bfr[2];
#pragma unroll
    for (int t = 0; t < 2; ++t) af[t] = *(const bf16x8*)(cA + (wrow + t * 16 + lr) * 32 + rchunk);
#pragma unroll
    for (int t = 0; t < 2; ++t) bfr[t] = *(const bf16x8*)(cB + (wcol + t * 16 + lr) * 32 + rchunk);
    if (step + 4 < 24) PSTG(step + 4, sb);
#pragma unroll
    for (int im = 0; im < 2; ++im)
#pragma unroll
      for (int in = 0; in < 2; ++in)
        acc[im][in] = __builtin_amdgcn_mfma_f32_16x16x32_bf16(af[im], bfr[in], acc[im][in], 0, 0, 0);
    __builtin_amdgcn_sched_barrier(0);
    if (step + 4 < 24)      asm volatile("s_waitcnt vmcnt(6) lgkmcnt(0)" ::: "memory");
    else if (step + 3 < 24) asm volatile("s_waitcnt vmcnt(4) lgkmcnt(0)" ::: "memory");
    else if (step + 2 < 24) asm volatile("s_waitcnt vmcnt(2) lgkmcnt(0)" ::: "memory");
    else                    asm volatile("s_waitcnt vmcnt(0) lgkmcnt(0)" ::: "memory");
    __builtin_amdgcn_s_barrier();
    rb = (rb + 1 == 5) ? 0 : rb + 1;
    sb = (sb + 1 == 5) ? 0 : sb + 1;
  }
#undef PSTG

  if (valid) {
#pragma unroll
    for (int im = 0; im < 2; ++im)
#pragma unroll
      for (int in = 0; in < 2; ++in) {
        int gn = n0 + wcol + in * 16 + lr;
        float bsv = bias[gn];
#pragma unroll
        for (int r = 0; r < 4; ++r) {
          int gm = m0 + wrow + im * 16 + lq * 4 + r;
          of32[(size_t)gm * 768 + gn] = acc[im][in][r] + bsv;
        }
      }
  }
}

// ---------------- the mega-kernel ----------------
__global__ __launch_bounds__(512, 2) void mega(const float* __restrict__ x,
                                               const float* __restrict__ qkv_w,
                                               const float* __restrict__ qkv_b,
                                               const float* __restrict__ proj_w,
                                               const float* __restrict__ proj_b,
                                               unsigned short* __restrict__ xb,
                                               unsigned short* __restrict__ wqkv,
                                               unsigned short* __restrict__ wproj,
                                               unsigned short* __restrict__ qkvt,
                                               unsigned short* __restrict__ vt,
                                               unsigned short* __restrict__ attnb,
                                               float* __restrict__ out) {
  __shared__ Smem sm;  // 128 KB union -> 1 block/CU; 256 blocks co-resident
  const int tid = threadIdx.x;
  const int bid = blockIdx.x;
  cg::grid_group grid = cg::this_grid();

  // ---- phase 1: cvt ----
  cvt_phase(bid * 512 + tid, 256 * 512, x, qkv_w, proj_w, xb, wqkv, wproj);
  __threadfence();
  grid.sync();

  // ---- phase 2: qkv GEMM (144 tiles; blocks >=144 idle through to the sync) ----
  if (bid < 144) qkv_tile(tid, bid, sm.g.a, sm.g.b, xb, wqkv, qkv_b, qkvt, vt);
  __threadfence();
  grid.sync();

  // ---- phase 3: natten (768 units; 2x 256-thr sub-units/block, 2 passes) ----
  {
    const int sub = tid >> 8, t2 = tid & 255;
    for (int pass = 0; pass < 2; ++pass) {
      if (pass) __syncthreads();  // protect LDS reuse across passes
      const int u = 3 * bid + (pass == 0 ? sub : 2);
      const bool valid = (pass == 0) || (sub == 0);
      natten_unit(t2, sm.n.k[sub], sm.n.v[sub], qkvt, attnb, u, valid);
    }
  }
  __threadfence();
  grid.sync();

  // ---- phase 4: proj (768 tiles; 2x 256-thr sub-units/block, 2 passes) ----
  {
    const int sub = tid >> 8, t2 = tid & 255;
    for (int pass = 0; pass < 2; ++pass) {
      if (pass) __syncthreads();
      const int t = 3 * bid + (pass == 0 ? sub : 2);
      const bool valid = (pass == 0) || (sub == 0);
      proj_unit(t2, sm.p.a[sub], sm.p.b[sub], attnb, wproj, proj_b, out,
                (t / 12) * 64, (t % 12) * 64, valid);
    }
  }
}

// ---------------- launch ----------------
extern "C" void kernel_launch(void* const* d_in, const int* in_sizes, int n_in,
                              void* d_out, int out_size, void* d_ws, size_t ws_size,
                              hipStream_t stream) {
  const float* x      = (const float*)d_in[0];
  const float* qkv_w  = (const float*)d_in[1];
  const float* qkv_b  = (const float*)d_in[2];
  const float* proj_w = (const float*)d_in[3];
  const float* proj_b = (const float*)d_in[4];
  char* ws = (char*)d_ws;

  unsigned short* xb    = (unsigned short*)(ws);                 // 4096*768 bf16
  unsigned short* wqkv  = (unsigned short*)(ws + 6291456);       // 2304*768 bf16
  unsigned short* wproj = (unsigned short*)(ws + 9830400);       // 768*768 bf16
  unsigned short* qkvt  = (unsigned short*)(ws + 11010048);      // Q,K token-major + Vt
  unsigned short* attnb = (unsigned short*)(ws + 29884416);      // 4096*768 bf16
  unsigned short* vt    = qkvt + (size_t)24 * 4096 * 64;         // V transposed [12][64][4096]
  float* out = (float*)d_out;

  void* kargs[] = {(void*)&x, (void*)&qkv_w, (void*)&qkv_b, (void*)&proj_w, (void*)&proj_b,
                   (void*)&xb, (void*)&wqkv, (void*)&wproj, (void*)&qkvt, (void*)&vt,
                   (void*)&attnb, (void*)&out};
  hipLaunchCooperativeKernel((const void*)mega, dim3(256), dim3(512), kargs, 0, stream);
}

// Round 8
// 144.700 us; speedup vs baseline: 2.7137x; 2.7137x over previous
//
#include <hip/hip_runtime.h>

// B=4, HG=WG=32 -> 1024 tokens/batch, 4096 total; D=768, NH=12, HD=64, K=7 (49 neighbors)

typedef __bf16 bf16x8 __attribute__((ext_vector_type(8)));
typedef short s16x4 __attribute__((ext_vector_type(4)));
typedef float f32x4 __attribute__((ext_vector_type(4)));

__device__ __forceinline__ unsigned short f2bf(float f) {
  unsigned u = __float_as_uint(f);
  u += 0x7fffu + ((u >> 16) & 1u);   // RNE
  return (unsigned short)(u >> 16);
}

template <typename T>
__device__ __forceinline__ void gld_lds16(const T* g, T* l) {
  __builtin_amdgcn_global_load_lds((const __attribute__((address_space(1))) void*)g,
                                   (__attribute__((address_space(3))) void*)l, 16, 0, 0);
}

// ---------------- fp32 -> bf16 conversion of x, qkv_w, proj_w ----------------
__global__ void cvt_kernel(const float* __restrict__ x, const float* __restrict__ w1,
                           const float* __restrict__ w2, unsigned short* __restrict__ xo,
                           unsigned short* __restrict__ w1o, unsigned short* __restrict__ w2o) {
  const int n1 = 4096 * 768 / 4;
  const int n2 = 2304 * 768 / 4;
  const int n3 = 768 * 768 / 4;
  int i = blockIdx.x * 256 + threadIdx.x;
  float4 v;
  unsigned short* dst;
  int o;
  if (i < n1) {
    o = i; v = ((const float4*)x)[o]; dst = xo;
  } else if (i < n1 + n2) {
    o = i - n1; v = ((const float4*)w1)[o]; dst = w1o;
  } else if (i < n1 + n2 + n3) {
    o = i - n1 - n2; v = ((const float4*)w2)[o]; dst = w2o;
  } else {
    return;
  }
  ushort4 r;
  r.x = f2bf(v.x); r.y = f2bf(v.y); r.z = f2bf(v.z); r.w = f2bf(v.w);
  ((ushort4*)dst)[o] = r;
}

// ---------------- bf16 GEMM, C = A * B^T + bias ----------------
// R8: wave-supply experiment. All qkv schedules (2-phase/counted/8-phase) stuck
// at ~44us with ALL pipes idle and ~2 waves/SIMD -> latency-bound from wave
// starvation (L3-dirty cross-XCD reads of cvt output; no HBM-visible traffic).
// Fix: qkv moves to 64x64 tiles (grid 36x64 = 2304 blocks, 9216 waves), 32 KB
// LDS (NB=4, depth-3), launch_bounds(256,4) -> 4-5 blocks/CU = 16-20 waves/CU
// (vs ~8). Counted-wait ladder re-derived for L=2/depth-3 (steady vmcnt(4)).
// Known cost: panel refetch from XCD-local L2 (~442MB -> ~13us L2 floor).
// MODE 1 (proj): unchanged R5 (64x64, NB=5, depth-4, steady vmcnt(6)).
template <int MODE, int BM, int BN>
__global__ __launch_bounds__(256, 4) void gemm_bt(const unsigned short* __restrict__ A,
                                                  const unsigned short* __restrict__ Bm,
                                                  const float* __restrict__ bias,
                                                  unsigned short* __restrict__ obf,
                                                  unsigned short* __restrict__ vtout,
                                                  float* __restrict__ of32,
                                                  int M, int N, int Kd) {
  constexpr int RA = BM / 64, RB = BN / 64;   // gld rounds per tile (per matrix)
  constexpr int MI = BM / 32, NI = BN / 32;   // 16x16 frags per wave
  constexpr int NB = (MODE == 0) ? 4 : 5;     // LDS buffers
  constexpr int DEPTH = NB - 1;               // tiles in flight ahead
  __shared__ __align__(16) unsigned short sA[NB][BM * 32];
  __shared__ __align__(16) unsigned short sB[NB][BN * 32];
  const int tid = threadIdx.x;
  const int lane = tid & 63;
  const int wv = tid >> 6;

  // XCD rectangles: qkv (36,64): HX=18, HY=16 -> 3.3 MB/XCD.
  // proj (12,64): HX=6, HY=16 -> 2.1 MB/XCD.
  constexpr int HX = (MODE == 0) ? 18 : 6;
  constexpr int HY = 16;
  const int lin = blockIdx.y * gridDim.x + blockIdx.x;
  const int xcd = lin & 7, rrr = lin >> 3;
  const int bx = (xcd & 1) * HX + rrr % HX;
  const int by = (xcd >> 1) * HY + rrr / HX;
  const int m0 = by * BM, n0 = bx * BN;

  const int wrow = (wv >> 1) * (BM / 2), wcol = (wv & 1) * (BN / 2);
  const int lr = lane & 15, lq = lane >> 4;
  // read-side swizzled chunk: physical chunk = lq ^ ((row>>1)&3); row = 16m+lr
  const int rchunk = (lq ^ ((lr >> 1) & 3)) * 8;

  f32x4 acc[MI][NI] = {};

  // source-side chunk swizzle matches read side (both-sides-or-neither).
  const int schunk = ((tid & 3) ^ ((tid >> 3) & 3)) * 8;
  const unsigned short* gA = A + (size_t)(m0 + (tid >> 2)) * Kd + schunk;
  const unsigned short* gB = Bm + (size_t)(n0 + (tid >> 2)) * Kd + schunk;

  const int NS = Kd >> 5;  // 32-wide k-steps (24 here)

#define STAGE_TILE(tile, bufidx)                                                          \
  do {                                                                                    \
    const int _off = (tile) * 32;                                                         \
    unsigned short* _dA = sA[(bufidx)];                                                   \
    unsigned short* _dB = sB[(bufidx)];                                                   \
    _Pragma("unroll")                                                                     \
    for (int _r = 0; _r < RA; ++_r)                                                       \
      gld_lds16(gA + (size_t)(_r * 64) * Kd + _off, _dA + _r * 2048 + tid * 8);           \
    _Pragma("unroll")                                                                     \
    for (int _r = 0; _r < RB; ++_r)                                                       \
      gld_lds16(gB + (size_t)(_r * 64) * Kd + _off, _dB + _r * 2048 + tid * 8);           \
  } while (0)

#pragma unroll
  for (int t = 0; t < DEPTH; ++t) STAGE_TILE(t, t);
  __builtin_amdgcn_sched_barrier(0);
  if constexpr (MODE == 0) asm volatile("s_waitcnt vmcnt(4) lgkmcnt(0)" ::: "memory");
  else                     asm volatile("s_waitcnt vmcnt(6) lgkmcnt(0)" ::: "memory");
  __builtin_amdgcn_s_barrier();

  int rb = 0, sb = DEPTH;
  for (int step = 0; step < NS; ++step) {
    const unsigned short* cA = sA[rb];
    const unsigned short* cB = sB[rb];
    bf16x8 af[MI], bfr[NI];
#pragma unroll
    for (int t = 0; t < MI; ++t) af[t] = *(const bf16x8*)(cA + (wrow + t * 16 + lr) * 32 + rchunk);
#pragma unroll
    for (int t = 0; t < NI; ++t) bfr[t] = *(const bf16x8*)(cB + (wcol + t * 16 + lr) * 32 + rchunk);

    if (step + DEPTH < NS) STAGE_TILE(step + DEPTH, sb);

#pragma unroll
    for (int im = 0; im < MI; ++im)
#pragma unroll
      for (int in = 0; in < NI; ++in)
        acc[im][in] = __builtin_amdgcn_mfma_f32_16x16x32_bf16(af[im], bfr[in], acc[im][in], 0, 0, 0);

    __builtin_amdgcn_sched_barrier(0);
    if constexpr (MODE == 0) {
      // L=2/tile, depth-3: steady 2 tiles (4 loads) in flight after wait
      if (step + 3 < NS)      asm volatile("s_waitcnt vmcnt(4) lgkmcnt(0)" ::: "memory");
      else if (step + 2 < NS) asm volatile("s_waitcnt vmcnt(2) lgkmcnt(0)" ::: "memory");
      else                    asm volatile("s_waitcnt vmcnt(0) lgkmcnt(0)" ::: "memory");
    } else {
      // L=2/tile, depth-4: steady 3 tiles (6 loads) in flight after wait
      if (step + 4 < NS)      asm volatile("s_waitcnt vmcnt(6) lgkmcnt(0)" ::: "memory");
      else if (step + 3 < NS) asm volatile("s_waitcnt vmcnt(4) lgkmcnt(0)" ::: "memory");
      else if (step + 2 < NS) asm volatile("s_waitcnt vmcnt(2) lgkmcnt(0)" ::: "memory");
      else                    asm volatile("s_waitcnt vmcnt(0) lgkmcnt(0)" ::: "memory");
    }
    __builtin_amdgcn_s_barrier();
    rb = (rb + 1 == NB) ? 0 : rb + 1;
    sb = (sb + 1 == NB) ? 0 : sb + 1;
  }
#undef STAGE_TILE

  if (MODE == 0) {
    const int sidx = n0 / 768;  // block-uniform (768 % BN == 0)
    if (sidx == 2) {
      // V -> transposed vt[(hh*64+dd)*4096 + token]
#pragma unroll
      for (int im = 0; im < MI; ++im) {
#pragma unroll
        for (int in = 0; in < NI; ++in) {
          int gn = n0 + wcol + in * 16 + lr;
          int rem = gn - 1536;
          int hh = rem >> 6, dd = gn & 63;
          float bsv = bias[gn];
          int gm0 = m0 + wrow + im * 16 + lq * 4;
          ushort4 pk;
          pk.x = f2bf(acc[im][in][0] + bsv);
          pk.y = f2bf(acc[im][in][1] + bsv);
          pk.z = f2bf(acc[im][in][2] + bsv);
          pk.w = f2bf(acc[im][in][3] + bsv);
          *(ushort4*)(vtout + (size_t)(hh * 64 + dd) * 4096 + gm0) = pk;
        }
      }
    } else {
      const float scale = (sidx == 0) ? 0.18033688f : 1.0f;  // 0.125 * log2(e) for Q
#pragma unroll
      for (int im = 0; im < MI; ++im) {
#pragma unroll
        for (int in = 0; in < NI; ++in) {
          int gn = n0 + wcol + in * 16 + lr;
          int rem = gn - sidx * 768;
          int hh = rem >> 6, dd = gn & 63;
          float bsv = bias[gn];
#pragma unroll
          for (int r = 0; r < 4; ++r) {
            int gm = m0 + wrow + im * 16 + lq * 4 + r;
            float val = (acc[im][in][r] + bsv) * scale;
            obf[((size_t)(sidx * 12 + hh) * 4096 + gm) * 64 + dd] = f2bf(val);
          }
        }
      }
    }
  } else {
#pragma unroll
    for (int im = 0; im < MI; ++im) {
#pragma unroll
      for (int in = 0; in < NI; ++in) {
        int gn = n0 + wcol + in * 16 + lr;
        float bsv = bias[gn];
#pragma unroll
        for (int r = 0; r < 4; ++r) {
          int gm = m0 + wrow + im * 16 + lq * 4 + r;
          of32[(size_t)gm * N + gn] = acc[im][in][r] + bsv;
        }
      }
    }
  }
}

// ---------------- neighborhood attention (MFMA) ----------------
// Proven R0/R1 version (72 KB LDS, 2 blocks/CU) — frozen.
__global__ __launch_bounds__(256, 2) void natten_kernel(const unsigned short* __restrict__ qkvt,
                                                        unsigned short* __restrict__ aout) {
  __shared__ __align__(16) unsigned short sQ[64 * 64];    //  8 KB
  __shared__ __align__(16) unsigned short sK[256 * 64];   // 32 KB
  __shared__ __align__(16) unsigned short sVt[64 * 256];  // 32 KB
  const int h = blockIdx.x, ip = blockIdx.y, b = blockIdx.z;
  const int i0 = ip * 2;
  const int tid = threadIdx.x, lane = tid & 63, wv = tid >> 6;
  const int lg = lane >> 4, lm = lane & 15;
  int si0 = i0 - 3; si0 = si0 < 0 ? 0 : si0; if (si0 > 25) si0 = 25;
  const int gb = b * 1024;
  const unsigned short* Qg = qkvt + ((size_t)h * 4096 + gb + i0 * 32) * 64;
  const unsigned short* Kg = qkvt + ((size_t)(12 + h) * 4096 + gb) * 64;
  const unsigned short* Vg = qkvt + (size_t)24 * 4096 * 64 + (size_t)h * 64 * 4096 + gb;

#pragma unroll
  for (int it = 0; it < 2; ++it) {  // Q: 64 q x 64 d
    int f = it * 256 + tid;
    int q = f >> 3, c16 = f & 7;
    uint4 v = *(const uint4*)(Qg + q * 64 + c16 * 8);
    int s = q & 15;
    *(uint2*)(sQ + q * 64 + ((((c16 << 1)) ^ s) << 2)) = make_uint2(v.x, v.y);
    *(uint2*)(sQ + q * 64 + ((((c16 << 1) | 1) ^ s) << 2)) = make_uint2(v.z, v.w);
  }
#pragma unroll
  for (int it = 0; it < 8; ++it) {  // K: 256 tok x 64 d
    int f = it * 256 + tid;
    int t = f >> 3, c16 = f & 7;
    int wr = t >> 5, c = t & 31;
    int row = si0 + wr; if (row > 31) row = 31;
    uint4 v = *(const uint4*)(Kg + (row * 32 + c) * 64 + c16 * 8);
    int s = t & 15;
    *(uint2*)(sK + t * 64 + ((((c16 << 1)) ^ s) << 2)) = make_uint2(v.x, v.y);
    *(uint2*)(sK + t * 64 + ((((c16 << 1) | 1) ^ s) << 2)) = make_uint2(v.z, v.w);
  }
#pragma unroll
  for (int it = 0; it < 8; ++it) {  // Vt: 64 d x 256 tok
    int f = it * 256 + tid;
    int d = f >> 5, tc16 = f & 31;
    int wr = tc16 >> 2;
    int row = si0 + wr; if (row > 31) row = 31;
    uint4 v = *(const uint4*)(Vg + (size_t)d * 4096 + row * 32 + (tc16 & 3) * 8);
    int s = d & 15;
    *(uint2*)(sVt + d * 256 + ((((tc16 << 1)) ^ s) << 2)) = make_uint2(v.x, v.y);
    *(uint2*)(sVt + d * 256 + ((((tc16 << 1) | 1) ^ s) << 2)) = make_uint2(v.z, v.w);
  }
  __syncthreads();

  const int row_sel = wv >> 1;
  const int jhalf = wv & 1;
  const int i = i0 + row_sel;
  int si_w = i - 3; si_w = si_w < 0 ? 0 : si_w; if (si_w > 25) si_w = 25;
  const int toff = (si_w - si0) * 32;
  const int j = jhalf * 16 + lm;
  int sj = j - 3; sj = sj < 0 ? 0 : sj; if (sj > 25) sj = 25;

  float madd[2][4];
#pragma unroll
  for (int p = 0; p < 2; ++p)
#pragma unroll
    for (int r = 0; r < 4; ++r) {
      int c = p * 16 + lg * 4 + r;
      madd[p][r] = (c >= sj && c <= sj + 6) ? 0.f : -1e30f;
    }

  s16x4 qf[4];
  const int qrow = row_sel * 32 + j;
#pragma unroll
  for (int ks = 0; ks < 4; ++ks)
    qf[ks] = *(const s16x4*)(sQ + qrow * 64 + ((((ks << 2) + lg) ^ (qrow & 15)) << 2));

  f32x4 accS[14];
#pragma unroll
  for (int tt = 0; tt < 14; ++tt) {
    f32x4 a = {0.f, 0.f, 0.f, 0.f};
    const int trow = toff + tt * 16 + lm;
    const unsigned short* kr = sK + trow * 64;
    const int sw = trow & 15;
#pragma unroll
    for (int ks = 0; ks < 4; ++ks) {
      s16x4 kf = *(const s16x4*)(kr + ((((ks << 2) + lg) ^ sw) << 2));
      a = __builtin_amdgcn_mfma_f32_16x16x16bf16_1k(kf, qf[ks], a, 0, 0, 0);
    }
    accS[tt] = a;
  }

  float mx = -3e38f;
#pragma unroll
  for (int tt = 0; tt < 14; ++tt)
#pragma unroll
    for (int r = 0; r < 4; ++r) {
      float v = accS[tt][r] + madd[tt & 1][r];
      accS[tt][r] = v;
      mx = fmaxf(mx, v);
    }
  mx = fmaxf(mx, __shfl_xor(mx, 16, 64));
  mx = fmaxf(mx, __shfl_xor(mx, 32, 64));
  float sum = 0.f;
#pragma unroll
  for (int tt = 0; tt < 14; ++tt)
#pragma unroll
    for (int r = 0; r < 4; ++r) {
      float p = exp2f(accS[tt][r] - mx);
      accS[tt][r] = p;
      sum += p;
    }
  sum += __shfl_xor(sum, 16, 64);
  sum += __shfl_xor(sum, 32, 64);
  const float inv = 1.f / sum;

  s16x4 pf[14];
#pragma unroll
  for (int tt = 0; tt < 14; ++tt) {
    union { unsigned u[2]; s16x4 v; } pk;
    pk.u[0] = ((unsigned)f2bf(accS[tt][1]) << 16) | f2bf(accS[tt][0]);
    pk.u[1] = ((unsigned)f2bf(accS[tt][3]) << 16) | f2bf(accS[tt][2]);
    pf[tt] = pk.v;
  }

  f32x4 accO[4] = {};
  const int choff = toff >> 2;
#pragma unroll
  for (int tt = 0; tt < 14; ++tt) {
    const int c8 = choff + tt * 4 + lg;
#pragma unroll
    for (int nt = 0; nt < 4; ++nt) {
      const int d = nt * 16 + lm;
      s16x4 vf = *(const s16x4*)(sVt + d * 256 + ((c8 ^ (d & 15)) << 2));
      accO[nt] = __builtin_amdgcn_mfma_f32_16x16x16bf16_1k(pf[tt], vf, accO[nt], 0, 0, 0);
    }
  }

  float invr[4];
#pragma unroll
  for (int r = 0; r < 4; ++r) invr[r] = __shfl(inv, lg * 4 + r, 64);

  const int tokbase = gb + i * 32 + jhalf * 16;
#pragma unroll
  for (int nt = 0; nt < 4; ++nt)
#pragma unroll
    for (int r = 0; r < 4; ++r) {
      int tok = tokbase + lg * 4 + r;
      aout[(size_t)tok * 768 + h * 64 + nt * 16 + lm] = f2bf(accO[nt][r] * invr[r]);
    }
}

// ---------------- launch ----------------
extern "C" void kernel_launch(void* const* d_in, const int* in_sizes, int n_in,
                              void* d_out, int out_size, void* d_ws, size_t ws_size,
                              hipStream_t stream) {
  const float* x      = (const float*)d_in[0];
  const float* qkv_w  = (const float*)d_in[1];
  const float* qkv_b  = (const float*)d_in[2];
  const float* proj_w = (const float*)d_in[3];
  const float* proj_b = (const float*)d_in[4];
  char* ws = (char*)d_ws;

  unsigned short* xb    = (unsigned short*)(ws);                 // 4096*768 bf16
  unsigned short* wqkv  = (unsigned short*)(ws + 6291456);       // 2304*768 bf16
  unsigned short* wproj = (unsigned short*)(ws + 9830400);       // 768*768 bf16
  unsigned short* qkvt  = (unsigned short*)(ws + 11010048);      // Q,K token-major + Vt
  unsigned short* attnb = (unsigned short*)(ws + 29884416);      // 4096*768 bf16
  unsigned short* vt    = qkvt + (size_t)24 * 4096 * 64;         // V transposed [12][64][4096]
  float* out = (float*)d_out;

  cvt_kernel<<<5376, 256, 0, stream>>>(x, qkv_w, proj_w, xb, wqkv, wproj);
  gemm_bt<0, 64, 64><<<dim3(36, 64), 256, 0, stream>>>(xb, wqkv, qkv_b, qkvt, vt, nullptr, 4096, 2304, 768);
  natten_kernel<<<dim3(12, 16, 4), 256, 0, stream>>>(qkvt, attnb);
  gemm_bt<1, 64, 64><<<dim3(12, 64), 256, 0, stream>>>(attnb, wproj, proj_b, nullptr, nullptr, out, 4096, 768, 768);
}

// Round 10
// 143.522 us; speedup vs baseline: 2.7359x; 1.0082x over previous
//
#include <hip/hip_runtime.h>

// B=4, HG=WG=32 -> 1024 tokens/batch, 4096 total; D=768, NH=12, HD=64, K=7 (49 neighbors)

typedef __bf16 bf16x8 __attribute__((ext_vector_type(8)));
typedef short s16x4 __attribute__((ext_vector_type(4)));
typedef float f32x4 __attribute__((ext_vector_type(4)));

__device__ __forceinline__ unsigned short f2bf(float f) {
  unsigned u = __float_as_uint(f);
  u += 0x7fffu + ((u >> 16) & 1u);   // RNE
  return (unsigned short)(u >> 16);
}

template <typename T>
__device__ __forceinline__ void gld_lds16(const T* g, T* l) {
  __builtin_amdgcn_global_load_lds((const __attribute__((address_space(1))) void*)g,
                                   (__attribute__((address_space(3))) void*)l, 16, 0, 0);
}

// ---------------- fp32 -> bf16 conversion of x, qkv_w, proj_w ----------------
__global__ void cvt_kernel(const float* __restrict__ x, const float* __restrict__ w1,
                           const float* __restrict__ w2, unsigned short* __restrict__ xo,
                           unsigned short* __restrict__ w1o, unsigned short* __restrict__ w2o) {
  const int n1 = 4096 * 768 / 4;
  const int n2 = 2304 * 768 / 4;
  const int n3 = 768 * 768 / 4;
  int i = blockIdx.x * 256 + threadIdx.x;
  float4 v;
  unsigned short* dst;
  int o;
  if (i < n1) {
    o = i; v = ((const float4*)x)[o]; dst = xo;
  } else if (i < n1 + n2) {
    o = i - n1; v = ((const float4*)w1)[o]; dst = w1o;
  } else if (i < n1 + n2 + n3) {
    o = i - n1 - n2; v = ((const float4*)w2)[o]; dst = w2o;
  } else {
    return;
  }
  ushort4 r;
  r.x = f2bf(v.x); r.y = f2bf(v.y); r.z = f2bf(v.z); r.w = f2bf(v.w);
  ((ushort4*)dst)[o] = r;
}

// ---------------- qkv GEMM: tri-buffered 4-phase 256x256, counted vmcnt never 0 ----------------
// R10 = R9 resubmit (R9 bench was an infra failure, no data). Rationale: R6's
// 8-phase port drained vmcnt(0) at every K-tile boundary -> guide m218:
// "8-phase-with-drain0 == 1-phase" (measured 44us == 2-phase's 44us). R5 had
// counted-never-0 but NO fine phase interleave (m196: null). This version has BOTH:
//   BK=32, 3 K-tile buffers (96 KB, 1 block/CU, 512 thr / 8 waves 2Mx4N).
//   Per K-tile: 4 phases {2 A-frag ds_reads (+4 B at ph0) || 1 gld_lds of tile
//   t+2 -> barrier -> setprio 8xMFMA -> barrier}. Tile t+2's buffer == (t-1)'s,
//   consumed before this tile's entry barrier -> race-free staging.
//   Boundary: vmcnt(4) (t+2's 4 loads STAY in flight; t+1's, issued a full tile
//   earlier, are landed). vmcnt(0) only in the 2-tile tail.
// Frag swizzle: chunk = lq ^ (row&3) ^ ((row>>2)&3) -> 2-way (free); source
// pre-swizzled with the same involution (rule 21, both-sides).
__global__ __launch_bounds__(512, 1) void gemm_qkv3(const unsigned short* __restrict__ A,
                                                    const unsigned short* __restrict__ Bm,
                                                    const float* __restrict__ bias,
                                                    unsigned short* __restrict__ obf,
                                                    unsigned short* __restrict__ vtout) {
  __shared__ __align__(16) unsigned short sA[3][256 * 32];  // 48 KB
  __shared__ __align__(16) unsigned short sB[3][256 * 32];  // 48 KB
  const int tid = threadIdx.x, lane = tid & 63, wv = tid >> 6;
  const int wr = wv >> 2, wc = wv & 3;        // wave -> (M-half, N-quarter)
  const int lr = lane & 15, lq = lane >> 4;

  // XCD chunking: 144 blocks = 8 XCDs x 18
  const int lin = blockIdx.x;
  const int wgid = (lin & 7) * 18 + (lin >> 3);
  const int bx = wgid % 9, by = wgid / 9;
  const int m0 = by * 256, n0 = bx * 256;

  // staging map: row = (tid>>2) + 128*round; physical chunk tid&3 (8 elems);
  // source fetches logical chunk (tid&3) ^ swz(row), swz(row)=(row&3)^((row>>2)&3)
  const int srow = tid >> 2;
  const int pchunk = (tid & 3) * 8;
  const int swz = (srow & 3) ^ ((srow >> 2) & 3);   // invariant under row+=128
  const unsigned short* gA = A + (size_t)(m0 + srow) * 768 + ((tid & 3) ^ swz) * 8;
  const unsigned short* gB = Bm + (size_t)(n0 + srow) * 768 + ((tid & 3) ^ swz) * 8;
  const int ldst = srow * 32 + pchunk;

  // frag-read swizzled chunk offset (elems); row&15 == lr for all frag rows
  const int fsw = (lq ^ (lr & 3) ^ ((lr >> 2) & 3)) * 8;

  f32x4 acc[8][4] = {};

#define STG(t2, ld)                                                                           \
  do {                                                                                        \
    unsigned short* d = (((ld) < 2) ? sA[(t2) % 3] : sB[(t2) % 3]) +                          \
                        ((((ld) & 1) != 0) ? 128 * 32 : 0) + ldst;                            \
    const unsigned short* g = (((ld) < 2) ? gA : gB) +                                        \
                              ((((ld) & 1) != 0) ? (size_t)128 * 768 : (size_t)0) + (t2) * 32;\
    gld_lds16(g, d);                                                                          \
  } while (0)

#define QPHASE(mfb, ld)                                                                       \
  do {                                                                                        \
    bf16x8 a0 = *(const bf16x8*)(cA + (wr * 128 + (mfb) * 16 + lr) * 32 + fsw);               \
    bf16x8 a1 = *(const bf16x8*)(cA + (wr * 128 + ((mfb) + 1) * 16 + lr) * 32 + fsw);         \
    if (stg) STG(t + 2, ld);                                                                  \
    __builtin_amdgcn_s_barrier();                                                             \
    __builtin_amdgcn_s_setprio(1);                                                            \
    _Pragma("unroll")                                                                         \
    for (int nf = 0; nf < 4; ++nf) {                                                          \
      acc[(mfb)][nf] =                                                                        \
          __builtin_amdgcn_mfma_f32_16x16x32_bf16(a0, bfr[nf], acc[(mfb)][nf], 0, 0, 0);      \
      acc[(mfb) + 1][nf] =                                                                    \
          __builtin_amdgcn_mfma_f32_16x16x32_bf16(a1, bfr[nf], acc[(mfb) + 1][nf], 0, 0, 0);  \
    }                                                                                         \
    __builtin_amdgcn_s_setprio(0);                                                            \
  } while (0)

  // prologue: tiles 0 and 1 staged (8 loads); wait tile 0 only (vmcnt(4))
  STG(0, 0); STG(0, 1); STG(0, 2); STG(0, 3);
  STG(1, 0); STG(1, 1); STG(1, 2); STG(1, 3);
  __builtin_amdgcn_sched_barrier(0);
  asm volatile("s_waitcnt vmcnt(4)" ::: "memory");
  __builtin_amdgcn_s_barrier();

  for (int t = 0; t < 24; ++t) {
    const unsigned short* cA = sA[t % 3];
    const unsigned short* cB = sB[t % 3];
    const bool stg = (t + 2 < 24);
    bf16x8 bfr[4];
#pragma unroll
    for (int nf = 0; nf < 4; ++nf)
      bfr[nf] = *(const bf16x8*)(cB + (wc * 64 + nf * 16 + lr) * 32 + fsw);

    QPHASE(0, 0);
    __builtin_amdgcn_s_barrier();
    QPHASE(2, 1);
    __builtin_amdgcn_s_barrier();
    QPHASE(4, 2);
    __builtin_amdgcn_s_barrier();
    QPHASE(6, 3);
    // boundary: tile t+1's loads (issued during t-1) must be landed; tile t+2's
    // 4 loads (issued this tile) STAY in flight.
    __builtin_amdgcn_sched_barrier(0);
    if (t < 22)       asm volatile("s_waitcnt vmcnt(4)" ::: "memory");
    else if (t == 22) asm volatile("s_waitcnt vmcnt(0)" ::: "memory");
    __builtin_amdgcn_s_barrier();
  }
#undef QPHASE
#undef STG

  // ---- epilogue: identical output mapping to R6 (acc[8][4] per wave) ----
  const int sidx = n0 / 768;  // block-uniform (768 = 3*256)
  if (sidx == 2) {
    // V -> transposed vt[(hh*64+dd)*4096 + token]
#pragma unroll
    for (int mf = 0; mf < 8; ++mf) {
#pragma unroll
      for (int nf = 0; nf < 4; ++nf) {
        int gn = n0 + wc * 64 + nf * 16 + lr;
        int rem = gn - 1536;
        int hh = rem >> 6, dd = gn & 63;
        float bsv = bias[gn];
        int gm0 = m0 + wr * 128 + mf * 16 + lq * 4;
        ushort4 pk;
        pk.x = f2bf(acc[mf][nf][0] + bsv);
        pk.y = f2bf(acc[mf][nf][1] + bsv);
        pk.z = f2bf(acc[mf][nf][2] + bsv);
        pk.w = f2bf(acc[mf][nf][3] + bsv);
        *(ushort4*)(vtout + (size_t)(hh * 64 + dd) * 4096 + gm0) = pk;
      }
    }
  } else {
    const float scale = (sidx == 0) ? 0.18033688f : 1.0f;  // 0.125 * log2(e) for Q
#pragma unroll
    for (int mf = 0; mf < 8; ++mf) {
#pragma unroll
      for (int nf = 0; nf < 4; ++nf) {
        int gn = n0 + wc * 64 + nf * 16 + lr;
        int rem = gn - sidx * 768;
        int hh = rem >> 6, dd = gn & 63;
        float bsv = bias[gn];
#pragma unroll
        for (int r = 0; r < 4; ++r) {
          int gm = m0 + wr * 128 + mf * 16 + lq * 4 + r;
          float val = (acc[mf][nf][r] + bsv) * scale;
          obf[((size_t)(sidx * 12 + hh) * 4096 + gm) * 64 + dd] = f2bf(val);
        }
      }
    }
  }
}

// ---------------- proj GEMM (R5 exact: 64x64, NB=5, depth-4 counted) ----------------
template <int MODE, int BM, int BN>
__global__ __launch_bounds__(256) void gemm_bt(const unsigned short* __restrict__ A,
                                               const unsigned short* __restrict__ Bm,
                                               const float* __restrict__ bias,
                                               unsigned short* __restrict__ obf,
                                               unsigned short* __restrict__ vtout,
                                               float* __restrict__ of32,
                                               int M, int N, int Kd) {
  constexpr int RA = BM / 64, RB = BN / 64;
  constexpr int MI = BM / 32, NI = BN / 32;
  constexpr int NB = (MODE == 0) ? 4 : 5;
  constexpr int DEPTH = NB - 1;
  __shared__ __align__(16) unsigned short sA[NB][BM * 32];
  __shared__ __align__(16) unsigned short sB[NB][BN * 32];
  const int tid = threadIdx.x;
  const int lane = tid & 63;
  const int wv = tid >> 6;

  constexpr int HX = (MODE == 0) ? 18 : 6;
  constexpr int HY = 16;
  const int lin = blockIdx.y * gridDim.x + blockIdx.x;
  const int xcd = lin & 7, rrr = lin >> 3;
  const int bx = (xcd & 1) * HX + rrr % HX;
  const int by = (xcd >> 1) * HY + rrr / HX;
  const int m0 = by * BM, n0 = bx * BN;

  const int wrow = (wv >> 1) * (BM / 2), wcol = (wv & 1) * (BN / 2);
  const int lr = lane & 15, lq = lane >> 4;
  const int rchunk = (lq ^ ((lr >> 1) & 3)) * 8;

  f32x4 acc[MI][NI] = {};

  const int schunk = ((tid & 3) ^ ((tid >> 3) & 3)) * 8;
  const unsigned short* gA = A + (size_t)(m0 + (tid >> 2)) * Kd + schunk;
  const unsigned short* gB = Bm + (size_t)(n0 + (tid >> 2)) * Kd + schunk;

  const int NS = Kd >> 5;

#define STAGE_TILE(tile, bufidx)                                                          \
  do {                                                                                    \
    const int _off = (tile) * 32;                                                         \
    unsigned short* _dA = sA[(bufidx)];                                                   \
    unsigned short* _dB = sB[(bufidx)];                                                   \
    _Pragma("unroll")                                                                     \
    for (int _r = 0; _r < RA; ++_r)                                                       \
      gld_lds16(gA + (size_t)(_r * 64) * Kd + _off, _dA + _r * 2048 + tid * 8);           \
    _Pragma("unroll")                                                                     \
    for (int _r = 0; _r < RB; ++_r)                                                       \
      gld_lds16(gB + (size_t)(_r * 64) * Kd + _off, _dB + _r * 2048 + tid * 8);           \
  } while (0)

#pragma unroll
  for (int t = 0; t < DEPTH; ++t) STAGE_TILE(t, t);
  __builtin_amdgcn_sched_barrier(0);
  asm volatile("s_waitcnt vmcnt(6) lgkmcnt(0)" ::: "memory");
  __builtin_amdgcn_s_barrier();

  int rb = 0, sb = DEPTH;
  for (int step = 0; step < NS; ++step) {
    const unsigned short* cA = sA[rb];
    const unsigned short* cB = sB[rb];
    bf16x8 af[MI], bfr[NI];
#pragma unroll
    for (int t = 0; t < MI; ++t) af[t] = *(const bf16x8*)(cA + (wrow + t * 16 + lr) * 32 + rchunk);
#pragma unroll
    for (int t = 0; t < NI; ++t) bfr[t] = *(const bf16x8*)(cB + (wcol + t * 16 + lr) * 32 + rchunk);

    if (step + DEPTH < NS) STAGE_TILE(step + DEPTH, sb);

#pragma unroll
    for (int im = 0; im < MI; ++im)
#pragma unroll
      for (int in = 0; in < NI; ++in)
        acc[im][in] = __builtin_amdgcn_mfma_f32_16x16x32_bf16(af[im], bfr[in], acc[im][in], 0, 0, 0);

    __builtin_amdgcn_sched_barrier(0);
    if (step + 4 < NS)      asm volatile("s_waitcnt vmcnt(6) lgkmcnt(0)" ::: "memory");
    else if (step + 3 < NS) asm volatile("s_waitcnt vmcnt(4) lgkmcnt(0)" ::: "memory");
    else if (step + 2 < NS) asm volatile("s_waitcnt vmcnt(2) lgkmcnt(0)" ::: "memory");
    else                    asm volatile("s_waitcnt vmcnt(0) lgkmcnt(0)" ::: "memory");
    __builtin_amdgcn_s_barrier();
    rb = (rb + 1 == NB) ? 0 : rb + 1;
    sb = (sb + 1 == NB) ? 0 : sb + 1;
  }
#undef STAGE_TILE

#pragma unroll
  for (int im = 0; im < MI; ++im) {
#pragma unroll
    for (int in = 0; in < NI; ++in) {
      int gn = n0 + wcol + in * 16 + lr;
      float bsv = bias[gn];
#pragma unroll
      for (int r = 0; r < 4; ++r) {
        int gm = m0 + wrow + im * 16 + lq * 4 + r;
        of32[(size_t)gm * N + gn] = acc[im][in][r] + bsv;
      }
    }
  }
}

// ---------------- neighborhood attention (MFMA) ----------------
// Proven R0/R1 version (72 KB LDS, 2 blocks/CU) — frozen.
__global__ __launch_bounds__(256, 2) void natten_kernel(const unsigned short* __restrict__ qkvt,
                                                        unsigned short* __restrict__ aout) {
  __shared__ __align__(16) unsigned short sQ[64 * 64];    //  8 KB
  __shared__ __align__(16) unsigned short sK[256 * 64];   // 32 KB
  __shared__ __align__(16) unsigned short sVt[64 * 256];  // 32 KB
  const int h = blockIdx.x, ip = blockIdx.y, b = blockIdx.z;
  const int i0 = ip * 2;
  const int tid = threadIdx.x, lane = tid & 63, wv = tid >> 6;
  const int lg = lane >> 4, lm = lane & 15;
  int si0 = i0 - 3; si0 = si0 < 0 ? 0 : si0; if (si0 > 25) si0 = 25;
  const int gb = b * 1024;
  const unsigned short* Qg = qkvt + ((size_t)h * 4096 + gb + i0 * 32) * 64;
  const unsigned short* Kg = qkvt + ((size_t)(12 + h) * 4096 + gb) * 64;
  const unsigned short* Vg = qkvt + (size_t)24 * 4096 * 64 + (size_t)h * 64 * 4096 + gb;

#pragma unroll
  for (int it = 0; it < 2; ++it) {  // Q: 64 q x 64 d
    int f = it * 256 + tid;
    int q = f >> 3, c16 = f & 7;
    uint4 v = *(const uint4*)(Qg + q * 64 + c16 * 8);
    int s = q & 15;
    *(uint2*)(sQ + q * 64 + ((((c16 << 1)) ^ s) << 2)) = make_uint2(v.x, v.y);
    *(uint2*)(sQ + q * 64 + ((((c16 << 1) | 1) ^ s) << 2)) = make_uint2(v.z, v.w);
  }
#pragma unroll
  for (int it = 0; it < 8; ++it) {  // K: 256 tok x 64 d
    int f = it * 256 + tid;
    int t = f >> 3, c16 = f & 7;
    int wr = t >> 5, c = t & 31;
    int row = si0 + wr; if (row > 31) row = 31;
    uint4 v = *(const uint4*)(Kg + (row * 32 + c) * 64 + c16 * 8);
    int s = t & 15;
    *(uint2*)(sK + t * 64 + ((((c16 << 1)) ^ s) << 2)) = make_uint2(v.x, v.y);
    *(uint2*)(sK + t * 64 + ((((c16 << 1) | 1) ^ s) << 2)) = make_uint2(v.z, v.w);
  }
#pragma unroll
  for (int it = 0; it < 8; ++it) {  // Vt: 64 d x 256 tok
    int f = it * 256 + tid;
    int d = f >> 5, tc16 = f & 31;
    int wr = tc16 >> 2;
    int row = si0 + wr; if (row > 31) row = 31;
    uint4 v = *(const uint4*)(Vg + (size_t)d * 4096 + row * 32 + (tc16 & 3) * 8);
    int s = d & 15;
    *(uint2*)(sVt + d * 256 + ((((tc16 << 1)) ^ s) << 2)) = make_uint2(v.x, v.y);
    *(uint2*)(sVt + d * 256 + ((((tc16 << 1) | 1) ^ s) << 2)) = make_uint2(v.z, v.w);
  }
  __syncthreads();

  const int row_sel = wv >> 1;
  const int jhalf = wv & 1;
  const int i = i0 + row_sel;
  int si_w = i - 3; si_w = si_w < 0 ? 0 : si_w; if (si_w > 25) si_w = 25;
  const int toff = (si_w - si0) * 32;
  const int j = jhalf * 16 + lm;
  int sj = j - 3; sj = sj < 0 ? 0 : sj; if (sj > 25) sj = 25;

  float madd[2][4];
#pragma unroll
  for (int p = 0; p < 2; ++p)
#pragma unroll
    for (int r = 0; r < 4; ++r) {
      int c = p * 16 + lg * 4 + r;
      madd[p][r] = (c >= sj && c <= sj + 6) ? 0.f : -1e30f;
    }

  s16x4 qf[4];
  const int qrow = row_sel * 32 + j;
#pragma unroll
  for (int ks = 0; ks < 4; ++ks)
    qf[ks] = *(const s16x4*)(sQ + qrow * 64 + ((((ks << 2) + lg) ^ (qrow & 15)) << 2));

  f32x4 accS[14];
#pragma unroll
  for (int tt = 0; tt < 14; ++tt) {
    f32x4 a = {0.f, 0.f, 0.f, 0.f};
    const int trow = toff + tt * 16 + lm;
    const unsigned short* kr = sK + trow * 64;
    const int sw = trow & 15;
#pragma unroll
    for (int ks = 0; ks < 4; ++ks) {
      s16x4 kf = *(const s16x4*)(kr + ((((ks << 2) + lg) ^ sw) << 2));
      a = __builtin_amdgcn_mfma_f32_16x16x16bf16_1k(kf, qf[ks], a, 0, 0, 0);
    }
    accS[tt] = a;
  }

  float mx = -3e38f;
#pragma unroll
  for (int tt = 0; tt < 14; ++tt)
#pragma unroll
    for (int r = 0; r < 4; ++r) {
      float v = accS[tt][r] + madd[tt & 1][r];
      accS[tt][r] = v;
      mx = fmaxf(mx, v);
    }
  mx = fmaxf(mx, __shfl_xor(mx, 16, 64));
  mx = fmaxf(mx, __shfl_xor(mx, 32, 64));
  float sum = 0.f;
#pragma unroll
  for (int tt = 0; tt < 14; ++tt)
#pragma unroll
    for (int r = 0; r < 4; ++r) {
      float p = exp2f(accS[tt][r] - mx);
      accS[tt][r] = p;
      sum += p;
    }
  sum += __shfl_xor(sum, 16, 64);
  sum += __shfl_xor(sum, 32, 64);
  const float inv = 1.f / sum;

  s16x4 pf[14];
#pragma unroll
  for (int tt = 0; tt < 14; ++tt) {
    union { unsigned u[2]; s16x4 v; } pk;
    pk.u[0] = ((unsigned)f2bf(accS[tt][1]) << 16) | f2bf(accS[tt][0]);
    pk.u[1] = ((unsigned)f2bf(accS[tt][3]) << 16) | f2bf(accS[tt][2]);
    pf[tt] = pk.v;
  }

  f32x4 accO[4] = {};
  const int choff = toff >> 2;
#pragma unroll
  for (int tt = 0; tt < 14; ++tt) {
    const int c8 = choff + tt * 4 + lg;
#pragma unroll
    for (int nt = 0; nt < 4; ++nt) {
      const int d = nt * 16 + lm;
      s16x4 vf = *(const s16x4*)(sVt + d * 256 + ((c8 ^ (d & 15)) << 2));
      accO[nt] = __builtin_amdgcn_mfma_f32_16x16x16bf16_1k(pf[tt], vf, accO[nt], 0, 0, 0);
    }
  }

  float invr[4];
#pragma unroll
  for (int r = 0; r < 4; ++r) invr[r] = __shfl(inv, lg * 4 + r, 64);

  const int tokbase = gb + i * 32 + jhalf * 16;
#pragma unroll
  for (int nt = 0; nt < 4; ++nt)
#pragma unroll
    for (int r = 0; r < 4; ++r) {
      int tok = tokbase + lg * 4 + r;
      aout[(size_t)tok * 768 + h * 64 + nt * 16 + lm] = f2bf(accO[nt][r] * invr[r]);
    }
}

// ---------------- launch ----------------
extern "C" void kernel_launch(void* const* d_in, const int* in_sizes, int n_in,
                              void* d_out, int out_size, void* d_ws, size_t ws_size,
                              hipStream_t stream) {
  const float* x      = (const float*)d_in[0];
  const float* qkv_w  = (const float*)d_in[1];
  const float* qkv_b  = (const float*)d_in[2];
  const float* proj_w = (const float*)d_in[3];
  const float* proj_b = (const float*)d_in[4];
  char* ws = (char*)d_ws;

  unsigned short* xb    = (unsigned short*)(ws);                 // 4096*768 bf16
  unsigned short* wqkv  = (unsigned short*)(ws + 6291456);       // 2304*768 bf16
  unsigned short* wproj = (unsigned short*)(ws + 9830400);       // 768*768 bf16
  unsigned short* qkvt  = (unsigned short*)(ws + 11010048);      // Q,K token-major + Vt
  unsigned short* attnb = (unsigned short*)(ws + 29884416);      // 4096*768 bf16
  unsigned short* vt    = qkvt + (size_t)24 * 4096 * 64;         // V transposed [12][64][4096]
  float* out = (float*)d_out;

  cvt_kernel<<<5376, 256, 0, stream>>>(x, qkv_w, proj_w, xb, wqkv, wproj);
  gemm_qkv3<<<144, 512, 0, stream>>>(xb, wqkv, qkv_b, qkvt, vt);
  natten_kernel<<<dim3(12, 16, 4), 256, 0, stream>>>(qkvt, attnb);
  gemm_bt<1, 64, 64><<<dim3(12, 64), 256, 0, stream>>>(attnb, wproj, proj_b, nullptr, nullptr, out, 4096, 768, 768);
}

// Round 11
// 137.867 us; speedup vs baseline: 2.8481x; 1.0410x over previous
//
#include <hip/hip_runtime.h>

// B=4, HG=WG=32 -> 1024 tokens/batch, 4096 total; D=768, NH=12, HD=64, K=7 (49 neighbors)
// R11: REVERT to the session-best R5 configuration (measured 135.4 us).
// Schedule-space summary (all within-problem A/B, qkv GEMM):
//   2-phase dbuf (R4) / depth-3 counted (R5) / 8-phase 256^2 (R6) /
//   64^2 high-occupancy (R8) / tri-buffer 4-phase counted-never-0 (R10)
//   -> ALL 44-47 us, MfmaUtil pinned ~11%, conflicts ~0, FETCH compulsory,
//   HBM <15%. Five distinct schedules, one invariant time: the qkv plateau is
//   environmental (small-dispatch latency/clock floor), not structural.
// Harness poison-fill (256 MB, ~44 us) is inside the timed window and fixed.

typedef __bf16 bf16x8 __attribute__((ext_vector_type(8)));
typedef short s16x4 __attribute__((ext_vector_type(4)));
typedef float f32x4 __attribute__((ext_vector_type(4)));

__device__ __forceinline__ unsigned short f2bf(float f) {
  unsigned u = __float_as_uint(f);
  u += 0x7fffu + ((u >> 16) & 1u);   // RNE
  return (unsigned short)(u >> 16);
}

template <typename T>
__device__ __forceinline__ void gld_lds16(const T* g, T* l) {
  __builtin_amdgcn_global_load_lds((const __attribute__((address_space(1))) void*)g,
                                   (__attribute__((address_space(3))) void*)l, 16, 0, 0);
}

// ---------------- fp32 -> bf16 conversion of x, qkv_w, proj_w ----------------
__global__ void cvt_kernel(const float* __restrict__ x, const float* __restrict__ w1,
                           const float* __restrict__ w2, unsigned short* __restrict__ xo,
                           unsigned short* __restrict__ w1o, unsigned short* __restrict__ w2o) {
  const int n1 = 4096 * 768 / 4;
  const int n2 = 2304 * 768 / 4;
  const int n3 = 768 * 768 / 4;
  int i = blockIdx.x * 256 + threadIdx.x;
  float4 v;
  unsigned short* dst;
  int o;
  if (i < n1) {
    o = i; v = ((const float4*)x)[o]; dst = xo;
  } else if (i < n1 + n2) {
    o = i - n1; v = ((const float4*)w1)[o]; dst = w1o;
  } else if (i < n1 + n2 + n3) {
    o = i - n1 - n2; v = ((const float4*)w2)[o]; dst = w2o;
  } else {
    return;
  }
  ushort4 r;
  r.x = f2bf(v.x); r.y = f2bf(v.y); r.z = f2bf(v.z); r.w = f2bf(v.w);
  ((ushort4*)dst)[o] = r;
}

// ---------------- bf16 GEMM, C = A * B^T + bias ----------------
// Session-best config (R5):
//   MODE 0 (qkv, BM=BN=128): 4 buffers, depth-3, steady wait vmcnt(8)  (64 KB LDS)
//   MODE 1 (proj, BM=BN=64): 5 buffers, depth-4, steady wait vmcnt(6)  (40 KB LDS)
// One raw s_barrier per k-step; buffer rotation race-free (stage of tile k+D
// lands in the buffer last read at step k-1, which the previous barrier fenced).
// XOR chunk swizzle both-sides (rule 21); XCD 2D-rectangle block swizzle.
template <int MODE, int BM, int BN>
__global__ __launch_bounds__(256) void gemm_bt(const unsigned short* __restrict__ A,
                                               const unsigned short* __restrict__ Bm,
                                               const float* __restrict__ bias,
                                               unsigned short* __restrict__ obf,
                                               unsigned short* __restrict__ vtout,
                                               float* __restrict__ of32,
                                               int M, int N, int Kd) {
  constexpr int RA = BM / 64, RB = BN / 64;   // gld rounds per tile (per matrix)
  constexpr int MI = BM / 32, NI = BN / 32;   // 16x16 frags per wave
  constexpr int NB = (MODE == 0) ? 4 : 5;     // LDS buffers
  constexpr int DEPTH = NB - 1;               // tiles in flight ahead
  __shared__ __align__(16) unsigned short sA[NB][BM * 32];
  __shared__ __align__(16) unsigned short sB[NB][BN * 32];
  const int tid = threadIdx.x;
  const int lane = tid & 63;
  const int wv = tid >> 6;

  // XCD rectangles: qkv (18,32): HX=9, HY=8 -> 3.3 MB/XCD. proj (12,64): HX=6, HY=16.
  constexpr int HX = (MODE == 0) ? 9 : 6;
  constexpr int HY = (MODE == 0) ? 8 : 16;
  const int lin = blockIdx.y * gridDim.x + blockIdx.x;
  const int xcd = lin & 7, rrr = lin >> 3;
  const int bx = (xcd & 1) * HX + rrr % HX;
  const int by = (xcd >> 1) * HY + rrr / HX;
  const int m0 = by * BM, n0 = bx * BN;

  const int wrow = (wv >> 1) * (BM / 2), wcol = (wv & 1) * (BN / 2);
  const int lr = lane & 15, lq = lane >> 4;
  // read-side swizzled chunk: physical chunk = lq ^ ((row>>1)&3); row = 16m+lr
  const int rchunk = (lq ^ ((lr >> 1) & 3)) * 8;

  f32x4 acc[MI][NI] = {};

  // source-side chunk swizzle matches read side (both-sides-or-neither).
  const int schunk = ((tid & 3) ^ ((tid >> 3) & 3)) * 8;
  const unsigned short* gA = A + (size_t)(m0 + (tid >> 2)) * Kd + schunk;
  const unsigned short* gB = Bm + (size_t)(n0 + (tid >> 2)) * Kd + schunk;

  const int NS = Kd >> 5;  // 32-wide k-steps (24 here)

#define STAGE_TILE(tile, bufidx)                                                          \
  do {                                                                                    \
    const int _off = (tile) * 32;                                                         \
    unsigned short* _dA = sA[(bufidx)];                                                   \
    unsigned short* _dB = sB[(bufidx)];                                                   \
    _Pragma("unroll")                                                                     \
    for (int _r = 0; _r < RA; ++_r)                                                       \
      gld_lds16(gA + (size_t)(_r * 64) * Kd + _off, _dA + _r * 2048 + tid * 8);           \
    _Pragma("unroll")                                                                     \
    for (int _r = 0; _r < RB; ++_r)                                                       \
      gld_lds16(gB + (size_t)(_r * 64) * Kd + _off, _dB + _r * 2048 + tid * 8);           \
  } while (0)

#pragma unroll
  for (int t = 0; t < DEPTH; ++t) STAGE_TILE(t, t);
  __builtin_amdgcn_sched_barrier(0);
  if constexpr (MODE == 0) asm volatile("s_waitcnt vmcnt(8) lgkmcnt(0)" ::: "memory");
  else                     asm volatile("s_waitcnt vmcnt(6) lgkmcnt(0)" ::: "memory");
  __builtin_amdgcn_s_barrier();

  int rb = 0, sb = DEPTH;  // read / stage buffer cursors (wrap at NB)
  for (int step = 0; step < NS; ++step) {
    const unsigned short* cA = sA[rb];
    const unsigned short* cB = sB[rb];
    bf16x8 af[MI], bfr[NI];
#pragma unroll
    for (int t = 0; t < MI; ++t) af[t] = *(const bf16x8*)(cA + (wrow + t * 16 + lr) * 32 + rchunk);
#pragma unroll
    for (int t = 0; t < NI; ++t) bfr[t] = *(const bf16x8*)(cB + (wcol + t * 16 + lr) * 32 + rchunk);

    if (step + DEPTH < NS) STAGE_TILE(step + DEPTH, sb);  // issue while MFMAs run

#pragma unroll
    for (int im = 0; im < MI; ++im)
#pragma unroll
      for (int in = 0; in < NI; ++in)
        acc[im][in] = __builtin_amdgcn_mfma_f32_16x16x32_bf16(af[im], bfr[in], acc[im][in], 0, 0, 0);

    __builtin_amdgcn_sched_barrier(0);  // pin stage-issues before the counted wait
    if constexpr (MODE == 0) {
      // L=4/tile: steady 2 tiles in flight after wait
      if (step + 3 < NS)      asm volatile("s_waitcnt vmcnt(8) lgkmcnt(0)" ::: "memory");
      else if (step + 2 < NS) asm volatile("s_waitcnt vmcnt(4) lgkmcnt(0)" ::: "memory");
      else                    asm volatile("s_waitcnt vmcnt(0) lgkmcnt(0)" ::: "memory");
    } else {
      // L=2/tile: steady 3 tiles in flight after wait
      if (step + 4 < NS)      asm volatile("s_waitcnt vmcnt(6) lgkmcnt(0)" ::: "memory");
      else if (step + 3 < NS) asm volatile("s_waitcnt vmcnt(4) lgkmcnt(0)" ::: "memory");
      else if (step + 2 < NS) asm volatile("s_waitcnt vmcnt(2) lgkmcnt(0)" ::: "memory");
      else                    asm volatile("s_waitcnt vmcnt(0) lgkmcnt(0)" ::: "memory");
    }
    __builtin_amdgcn_s_barrier();
    rb = (rb + 1 == NB) ? 0 : rb + 1;
    sb = (sb + 1 == NB) ? 0 : sb + 1;
  }
#undef STAGE_TILE

  if (MODE == 0) {
    const int sidx = n0 / 768;  // block-uniform (768 % BN == 0)
    if (sidx == 2) {
      // V -> transposed vt[(hh*64+dd)*4096 + token]
#pragma unroll
      for (int im = 0; im < MI; ++im) {
#pragma unroll
        for (int in = 0; in < NI; ++in) {
          int gn = n0 + wcol + in * 16 + lr;
          int rem = gn - 1536;
          int hh = rem >> 6, dd = gn & 63;
          float bsv = bias[gn];
          int gm0 = m0 + wrow + im * 16 + lq * 4;
          ushort4 pk;
          pk.x = f2bf(acc[im][in][0] + bsv);
          pk.y = f2bf(acc[im][in][1] + bsv);
          pk.z = f2bf(acc[im][in][2] + bsv);
          pk.w = f2bf(acc[im][in][3] + bsv);
          *(ushort4*)(vtout + (size_t)(hh * 64 + dd) * 4096 + gm0) = pk;
        }
      }
    } else {
      const float scale = (sidx == 0) ? 0.18033688f : 1.0f;  // 0.125 * log2(e) for Q
#pragma unroll
      for (int im = 0; im < MI; ++im) {
#pragma unroll
        for (int in = 0; in < NI; ++in) {
          int gn = n0 + wcol + in * 16 + lr;
          int rem = gn - sidx * 768;
          int hh = rem >> 6, dd = gn & 63;
          float bsv = bias[gn];
#pragma unroll
          for (int r = 0; r < 4; ++r) {
            int gm = m0 + wrow + im * 16 + lq * 4 + r;
            float val = (acc[im][in][r] + bsv) * scale;
            obf[((size_t)(sidx * 12 + hh) * 4096 + gm) * 64 + dd] = f2bf(val);
          }
        }
      }
    }
  } else {
#pragma unroll
    for (int im = 0; im < MI; ++im) {
#pragma unroll
      for (int in = 0; in < NI; ++in) {
        int gn = n0 + wcol + in * 16 + lr;
        float bsv = bias[gn];
#pragma unroll
        for (int r = 0; r < 4; ++r) {
          int gm = m0 + wrow + im * 16 + lq * 4 + r;
          of32[(size_t)gm * N + gn] = acc[im][in][r] + bsv;
        }
      }
    }
  }
}

// ---------------- neighborhood attention (MFMA) ----------------
// Proven R0/R1 version (72 KB LDS, 2 blocks/CU).
// Block = (head, query-row-pair, batch): 64 queries, stages 8 KV grid rows (256 tok).
// S^T = K·Q^T via mfma_16x16x16_bf16: C-layout (col=lane&15=q, row=lg*4+reg=t) is
// EXACTLY the A-operand layout of PV -> P stays in registers.
__global__ __launch_bounds__(256, 2) void natten_kernel(const unsigned short* __restrict__ qkvt,
                                                        unsigned short* __restrict__ aout) {
  __shared__ __align__(16) unsigned short sQ[64 * 64];    //  8 KB
  __shared__ __align__(16) unsigned short sK[256 * 64];   // 32 KB
  __shared__ __align__(16) unsigned short sVt[64 * 256];  // 32 KB
  const int h = blockIdx.x, ip = blockIdx.y, b = blockIdx.z;
  const int i0 = ip * 2;
  const int tid = threadIdx.x, lane = tid & 63, wv = tid >> 6;
  const int lg = lane >> 4, lm = lane & 15;
  int si0 = i0 - 3; si0 = si0 < 0 ? 0 : si0; if (si0 > 25) si0 = 25;
  const int gb = b * 1024;
  const unsigned short* Qg = qkvt + ((size_t)h * 4096 + gb + i0 * 32) * 64;
  const unsigned short* Kg = qkvt + ((size_t)(12 + h) * 4096 + gb) * 64;
  const unsigned short* Vg = qkvt + (size_t)24 * 4096 * 64 + (size_t)h * 64 * 4096 + gb;

  // ---- staging (16B global loads, two 8B LDS writes w/ 4-bit XOR chunk swizzle) ----
#pragma unroll
  for (int it = 0; it < 2; ++it) {  // Q: 64 q x 64 d
    int f = it * 256 + tid;
    int q = f >> 3, c16 = f & 7;
    uint4 v = *(const uint4*)(Qg + q * 64 + c16 * 8);
    int s = q & 15;
    *(uint2*)(sQ + q * 64 + ((((c16 << 1)) ^ s) << 2)) = make_uint2(v.x, v.y);
    *(uint2*)(sQ + q * 64 + ((((c16 << 1) | 1) ^ s) << 2)) = make_uint2(v.z, v.w);
  }
#pragma unroll
  for (int it = 0; it < 8; ++it) {  // K: 256 tok x 64 d
    int f = it * 256 + tid;
    int t = f >> 3, c16 = f & 7;
    int wr = t >> 5, c = t & 31;
    int row = si0 + wr; if (row > 31) row = 31;
    uint4 v = *(const uint4*)(Kg + (row * 32 + c) * 64 + c16 * 8);
    int s = t & 15;
    *(uint2*)(sK + t * 64 + ((((c16 << 1)) ^ s) << 2)) = make_uint2(v.x, v.y);
    *(uint2*)(sK + t * 64 + ((((c16 << 1) | 1) ^ s) << 2)) = make_uint2(v.z, v.w);
  }
#pragma unroll
  for (int it = 0; it < 8; ++it) {  // Vt: 64 d x 256 tok
    int f = it * 256 + tid;
    int d = f >> 5, tc16 = f & 31;
    int wr = tc16 >> 2;
    int row = si0 + wr; if (row > 31) row = 31;
    uint4 v = *(const uint4*)(Vg + (size_t)d * 4096 + row * 32 + (tc16 & 3) * 8);
    int s = d & 15;
    *(uint2*)(sVt + d * 256 + ((((tc16 << 1)) ^ s) << 2)) = make_uint2(v.x, v.y);
    *(uint2*)(sVt + d * 256 + ((((tc16 << 1) | 1) ^ s) << 2)) = make_uint2(v.z, v.w);
  }
  __syncthreads();

  const int row_sel = wv >> 1;
  const int jhalf = wv & 1;
  const int i = i0 + row_sel;
  int si_w = i - 3; si_w = si_w < 0 ? 0 : si_w; if (si_w > 25) si_w = 25;
  const int toff = (si_w - si0) * 32;
  const int j = jhalf * 16 + lm;
  int sj = j - 3; sj = sj < 0 ? 0 : sj; if (sj > 25) sj = 25;

  // column mask: token col c depends only on (tile parity, lg, reg)
  float madd[2][4];
#pragma unroll
  for (int p = 0; p < 2; ++p)
#pragma unroll
    for (int r = 0; r < 4; ++r) {
      int c = p * 16 + lg * 4 + r;
      madd[p][r] = (c >= sj && c <= sj + 6) ? 0.f : -1e30f;
    }

  // Q B-fragments (held in regs, reused across all token tiles)
  s16x4 qf[4];
  const int qrow = row_sel * 32 + j;
#pragma unroll
  for (int ks = 0; ks < 4; ++ks)
    qf[ks] = *(const s16x4*)(sQ + qrow * 64 + ((((ks << 2) + lg) ^ (qrow & 15)) << 2));

  // S^T = K · Q^T
  f32x4 accS[14];
#pragma unroll
  for (int tt = 0; tt < 14; ++tt) {
    f32x4 a = {0.f, 0.f, 0.f, 0.f};
    const int trow = toff + tt * 16 + lm;
    const unsigned short* kr = sK + trow * 64;
    const int sw = trow & 15;
#pragma unroll
    for (int ks = 0; ks < 4; ++ks) {
      s16x4 kf = *(const s16x4*)(kr + ((((ks << 2) + lg) ^ sw) << 2));
      a = __builtin_amdgcn_mfma_f32_16x16x16bf16_1k(kf, qf[ks], a, 0, 0, 0);
    }
    accS[tt] = a;
  }

  // masked softmax (base-2; scale pre-folded into Q)
  float mx = -3e38f;
#pragma unroll
  for (int tt = 0; tt < 14; ++tt)
#pragma unroll
    for (int r = 0; r < 4; ++r) {
      float v = accS[tt][r] + madd[tt & 1][r];
      accS[tt][r] = v;
      mx = fmaxf(mx, v);
    }
  mx = fmaxf(mx, __shfl_xor(mx, 16, 64));
  mx = fmaxf(mx, __shfl_xor(mx, 32, 64));
  float sum = 0.f;
#pragma unroll
  for (int tt = 0; tt < 14; ++tt)
#pragma unroll
    for (int r = 0; r < 4; ++r) {
      float p = exp2f(accS[tt][r] - mx);
      accS[tt][r] = p;
      sum += p;
    }
  sum += __shfl_xor(sum, 16, 64);
  sum += __shfl_xor(sum, 32, 64);
  const float inv = 1.f / sum;

  // P fp32 -> bf16 A-fragments (register-direct, no LDS round-trip)
  s16x4 pf[14];
#pragma unroll
  for (int tt = 0; tt < 14; ++tt) {
    union { unsigned u[2]; s16x4 v; } pk;
    pk.u[0] = ((unsigned)f2bf(accS[tt][1]) << 16) | f2bf(accS[tt][0]);
    pk.u[1] = ((unsigned)f2bf(accS[tt][3]) << 16) | f2bf(accS[tt][2]);
    pf[tt] = pk.v;
  }

  // O = P · V
  f32x4 accO[4] = {};
  const int choff = toff >> 2;
#pragma unroll
  for (int tt = 0; tt < 14; ++tt) {
    const int c8 = choff + tt * 4 + lg;
#pragma unroll
    for (int nt = 0; nt < 4; ++nt) {
      const int d = nt * 16 + lm;
      s16x4 vf = *(const s16x4*)(sVt + d * 256 + ((c8 ^ (d & 15)) << 2));
      accO[nt] = __builtin_amdgcn_mfma_f32_16x16x16bf16_1k(pf[tt], vf, accO[nt], 0, 0, 0);
    }
  }

  // 1/sum per output row (O C-layout row = q = lg*4+reg)
  float invr[4];
#pragma unroll
  for (int r = 0; r < 4; ++r) invr[r] = __shfl(inv, lg * 4 + r, 64);

  const int tokbase = gb + i * 32 + jhalf * 16;
#pragma unroll
  for (int nt = 0; nt < 4; ++nt)
#pragma unroll
    for (int r = 0; r < 4; ++r) {
      int tok = tokbase + lg * 4 + r;
      aout[(size_t)tok * 768 + h * 64 + nt * 16 + lm] = f2bf(accO[nt][r] * invr[r]);
    }
}

// ---------------- launch ----------------
extern "C" void kernel_launch(void* const* d_in, const int* in_sizes, int n_in,
                              void* d_out, int out_size, void* d_ws, size_t ws_size,
                              hipStream_t stream) {
  const float* x      = (const float*)d_in[0];
  const float* qkv_w  = (const float*)d_in[1];
  const float* qkv_b  = (const float*)d_in[2];
  const float* proj_w = (const float*)d_in[3];
  const float* proj_b = (const float*)d_in[4];
  char* ws = (char*)d_ws;

  unsigned short* xb    = (unsigned short*)(ws);                 // 4096*768 bf16
  unsigned short* wqkv  = (unsigned short*)(ws + 6291456);       // 2304*768 bf16
  unsigned short* wproj = (unsigned short*)(ws + 9830400);       // 768*768 bf16
  unsigned short* qkvt  = (unsigned short*)(ws + 11010048);      // Q,K token-major + Vt
  unsigned short* attnb = (unsigned short*)(ws + 29884416);      // 4096*768 bf16
  unsigned short* vt    = qkvt + (size_t)24 * 4096 * 64;         // V transposed [12][64][4096]
  float* out = (float*)d_out;

  cvt_kernel<<<5376, 256, 0, stream>>>(x, qkv_w, proj_w, xb, wqkv, wproj);
  gemm_bt<0, 128, 128><<<dim3(18, 32), 256, 0, stream>>>(xb, wqkv, qkv_b, qkvt, vt, nullptr, 4096, 2304, 768);
  natten_kernel<<<dim3(12, 16, 4), 256, 0, stream>>>(qkvt, attnb);
  gemm_bt<1, 64, 64><<<dim3(12, 64), 256, 0, stream>>>(attnb, wproj, proj_b, nullptr, nullptr, out, 4096, 768, 768);
}